// Round 5
// baseline (1037.855 us; speedup 1.0000x reference)
//
#include <hip/hip_runtime.h>
#include <hip/hip_bf16.h>
#include <stdint.h>
#include <stddef.h>

#define NN 100000
#define NE 300000
#define FINDIM 128
#define HD 256
#define NG 4000
#define NLAYER 5
#define MPAD 100096   // multiple of 32; pad rows kept == 0.0f always
#define NT (MPAD/32)  // 3128 m-tiles of 32 rows
#define MG 384        // m-groups; grid = 2*MG

typedef __attribute__((ext_vector_type(8))) short bf8;
typedef __attribute__((ext_vector_type(4))) float f4;
typedef __attribute__((ext_vector_type(2))) float f2;

#define FENCE() __asm__ volatile("" ::: "memory")
#define WAITLGKM() __asm__ volatile("s_waitcnt lgkmcnt(0)" ::: "memory")
#define BARRIER() do { FENCE(); __builtin_amdgcn_s_barrier(); FENCE(); } while(0)

__device__ __forceinline__ unsigned short f2bf(float f){
  union { float f; unsigned u; } uf; uf.f = f;
  unsigned r = uf.u + 0x7fffu + ((uf.u >> 16) & 1u);
  return (unsigned short)(r >> 16);
}
__device__ __forceinline__ float bf2f(unsigned short h){
  union { unsigned u; float f; } uf; uf.u = ((unsigned)h) << 16; return uf.f;
}

// packed-f32 FMA (gfx90a+ FeaturePackedFP32Ops; present on gfx950)
__device__ __forceinline__ f2 pk_fma(f2 a, f2 b, f2 c){
  f2 d;
  asm("v_pk_fma_f32 %0, %1, %2, %3" : "=v"(d) : "v"(a), "v"(b), "v"(c));
  return d;
}
// unpack 2 bf16 (one u32 word) -> f2
__device__ __forceinline__ f2 up2(unsigned wd){
  union { unsigned u; float f; } a, b;
  a.u = wd << 16; b.u = wd & 0xffff0000u;
  return (f2){a.f, b.f};
}

// ---------------- zero fill ----------------
__global__ void k_zero(int* __restrict__ p, int n){
  int i = blockIdx.x*256 + threadIdx.x;
  if(i < n) p[i] = 0;
}

// ---------------- CSR build ----------------
__global__ void k_count(const int* __restrict__ ei, int* __restrict__ counts){
  int e = blockIdx.x*256 + threadIdx.x;
  if(e < NE) atomicAdd(&counts[ei[NE + e]], 1);
}

__global__ void k_scan_partial(const int* __restrict__ counts, int* __restrict__ partials){
  __shared__ int sw[4];
  int b = blockIdx.x, t = threadIdx.x;
  int base = b*1024 + t*4;
  int s = 0;
  #pragma unroll
  for(int j=0;j<4;j++){ int i = base+j; if(i < NN) s += counts[i]; }
  #pragma unroll
  for(int d=1; d<64; d<<=1) s += __shfl_xor(s, d, 64);
  if((t & 63) == 0) sw[t>>6] = s;
  __syncthreads();
  if(t == 0) partials[b] = sw[0]+sw[1]+sw[2]+sw[3];
}

__global__ void k_scan_tot(int* __restrict__ partials, int* __restrict__ offsets, int nb){
  __shared__ int sm[128];
  int t = threadIdx.x;
  int v = (t < nb) ? partials[t] : 0;
  sm[t] = v; __syncthreads();
  for(int d=1; d<128; d<<=1){
    int x = 0;
    if(t >= d) x = sm[t-d];
    __syncthreads();
    sm[t] += x;
    __syncthreads();
  }
  if(t < nb) partials[t] = sm[t] - v;   // exclusive
  if(t == 127) offsets[NN] = sm[127];   // total == NE
}

__global__ void k_scan_final(const int* __restrict__ counts, const int* __restrict__ partials,
                             int* __restrict__ offsets, int* __restrict__ cursor){
  __shared__ int wsum[4];
  int b = blockIdx.x, t = threadIdx.x;
  int base = b*1024 + t*4;
  int c[4]; int ts = 0;
  #pragma unroll
  for(int j=0;j<4;j++){ int i = base+j; c[j] = (i < NN) ? counts[i] : 0; ts += c[j]; }
  int lane = t & 63;
  int inc = ts;
  #pragma unroll
  for(int d=1; d<64; d<<=1){ int x = __shfl_up(inc, d, 64); if(lane >= d) inc += x; }
  if(lane == 63) wsum[t>>6] = inc;
  __syncthreads();
  int woff = 0;
  for(int w2=0; w2<(t>>6); w2++) woff += wsum[w2];
  int excl = partials[b] + woff + inc - ts;
  #pragma unroll
  for(int j=0;j<4;j++){
    int i = base+j;
    if(i < NN){ offsets[i] = excl; cursor[i] = excl; excl += c[j]; }
  }
}

__global__ void k_fill(const int* __restrict__ ei, int* __restrict__ cursor, int* __restrict__ eidx){
  int e = blockIdx.x*256 + threadIdx.x;
  if(e < NE){
    int d = ei[NE + e];
    int pos = atomicAdd(&cursor[d], 1);
    eidx[pos] = ei[e];
  }
}

// ---------------- weight transpose/convert ----------------
__global__ void k_wt(const float* __restrict__ src, unsigned short* __restrict__ dst, int K, int Ncols){
  int l = blockIdx.y;
  size_t base = (size_t)l * K * Ncols;
  int i = blockIdx.x*256 + threadIdx.x;
  if(i < K*Ncols){
    int k = i / Ncols, n = i % Ncols;
    dst[base + (size_t)n*K + k] = f2bf(src[base + i]);
  }
}

// ---------------- GEMM, B-in-regs, REG-STAGED A, static 2x rotation ----------------
// Grid 2*MG. Block 256 thr / 4 waves; wave tile 32m x 32n. 2 LDS A-buffers.
// Tile j lives in reg set (j&1): even->ra, odd->rb. body(k, cur, nxt, buf):
//   MFMA on As[buf]=tile k; refill cur (freed: tile k hit LDS last body) with
//   tile k+2; epilogue; store nxt (tile k+1) -> As[buf^1]; lgkm; s_barrier.
// Call sites bind cur/nxt STATICALLY (rule #20: no runtime reg-set select;
// R4's k&1-conditional sent ra/rb to scratch -> WRITE_SIZE 151MB).
// Raw s_barrier doesn't drain vmcnt; compiler inserts counted vmcnt from
// register deps, so tile-k+2 loads stay in flight across the barrier.
template<int TRANS, bool RELUOUT, bool STATS>
__global__ __launch_bounds__(256, 3) void k_gemmb(
    const unsigned short* __restrict__ A, const unsigned short* __restrict__ Bt,
    const float* __restrict__ bias, const float* __restrict__ preS,
    const float* __restrict__ preT, unsigned short* __restrict__ C,
    float* __restrict__ stats)
{
  __shared__ __align__(16) unsigned short As[2][8192];   // 32 KB: 2 x (32r x 256k)
  __shared__ __align__(16) unsigned short Cs[4][576];    // 4.5 KB: per-wave 16 x 36
  const int t = threadIdx.x;
  const int lane = t & 63, w = t >> 6;
  const int q = lane >> 4, ln = lane & 15;
  const int nh = blockIdx.x & 1;
  const int mg = blockIdx.x >> 1;
  const int nbase = nh*128 + w*32;

  // B fragments resident in registers (L2-resident 128 KB weight)
  bf8 bb[2][8];
  #pragma unroll
  for(int nf=0; nf<2; nf++)
    #pragma unroll
    for(int s=0; s<8; s++)
      bb[nf][s] = *(const bf8*)(Bt + (size_t)(nbase + nf*16 + ln)*HD + s*32 + q*8);

  float bv[2];
  #pragma unroll
  for(int nf=0; nf<2; nf++) bv[nf] = bias[nbase + nf*16 + ln];

  // TRANS scale/shift in registers (16 VGPR), loaded once from global
  f4 sA = (f4){0.f,0.f,0.f,0.f}, sB = sA, tA = sA, tB = sA;
  if(TRANS){
    int cc = (t & 31) * 8;
    sA = *(const f4*)(preS + cc);  sB = *(const f4*)(preS + cc + 4);
    tA = *(const f4*)(preT + cc);  tB = *(const f4*)(preT + cc + 4);
  }

  // reg-staged A: thread t handles LDS slots (j*256+t), j=0..3
  // LDS[slot] <- A[m0 + row][c] with row = j*8 + (t>>5), c = (t&31)^(row&7)
  auto loadA = [&](int mt, uint4 (&rg)[4]){
    const int m0 = mt*32;
    #pragma unroll
    for(int j=0; j<4; j++){
      int row = j*8 + (t>>5);
      int c = (t&31) ^ (row & 7);
      rg[j] = *(const uint4*)(A + (size_t)(m0 + row)*HD + c*8);
    }
  };
  auto storeA = [&](int b, uint4 (&rg)[4]){
    #pragma unroll
    for(int j=0; j<4; j++)
      *(uint4*)&As[b][(j*256 + t)*8] = rg[j];
  };

  float sacc[2] = {0.f, 0.f}, ssacc[2] = {0.f, 0.f};

  const int kt = (NT - 1 - mg)/MG + 1;   // 8 or 9 tiles for this block

  uint4 ra[4], rb[4];
  loadA(mg, ra);                 // tile 0 (even -> ra)
  loadA(mg + MG, rb);            // tile 1 (odd -> rb); kt >= 8 always
  storeA(0, ra);                 // compiler waits vmcnt for ra only
  WAITLGKM();
  BARRIER();

  auto body = [&](int k, uint4 (&cur)[4], uint4 (&nxt)[4], int buf){
    const int mt = mg + k*MG;
    const int m0 = mt*32;
    const bool padt = (m0 >= NN);       // block-uniform; pad tiles are trailing
    const bool hn  = (mt + MG   < NT);  // block-uniform
    const bool hn2 = (mt + 2*MG < NT);  // block-uniform
    unsigned short* Ab = &As[buf][0];

    if(padt){
      uint4 z = (uint4){0u,0u,0u,0u};
      int r2 = lane >> 2, sg = lane & 3;
      *(uint4*)&C[(size_t)(m0 + r2)*HD + nbase + sg*8]      = z;
      *(uint4*)&C[(size_t)(m0 + 16 + r2)*HD + nbase + sg*8] = z;
      if(hn2) loadA(mt + 2*MG, cur);
    } else {
      if(TRANS){
        const int r0 = t >> 5;
        const int p  = (t & 31) ^ r0;
        #pragma unroll
        for(int i=0; i<4; i++){
          int row = r0 + 8*i;
          uint4 u = *(uint4*)&Ab[(row*32 + p)*8];
          unsigned short* us = (unsigned short*)&u;
          #pragma unroll
          for(int e=0; e<8; e++){
            float sc = (e<4) ? sA[e] : sB[e-4];
            float sh = (e<4) ? tA[e] : tB[e-4];
            float v = bf2f(us[e]);
            v = fmaxf(fmaf(sc, v, sh), 0.f);
            us[e] = f2bf(v);
          }
          *(uint4*)&Ab[(row*32 + p)*8] = u;
        }
        WAITLGKM();
        BARRIER();                      // transformed tile visible to all waves
      }

      f4 acc[2][2];
      #pragma unroll
      for(int i=0;i<2;i++)
        #pragma unroll
        for(int j=0;j<2;j++) acc[i][j] = (f4){0.f,0.f,0.f,0.f};

      __builtin_amdgcn_s_setprio(1);
      #pragma unroll
      for(int s=0; s<8; s++){
        bf8 af[2];
        #pragma unroll
        for(int mi=0; mi<2; mi++){
          int row = mi*16 + ln;
          int p = (s*4 + q) ^ (row & 7);
          af[mi] = *(const bf8*)&Ab[row*256 + p*8];
        }
        #pragma unroll
        for(int mi=0; mi<2; mi++)
          #pragma unroll
          for(int nf=0; nf<2; nf++)
            acc[mi][nf] = __builtin_amdgcn_mfma_f32_16x16x32_bf16(af[mi], bb[nf][s], acc[mi][nf], 0, 0, 0);
      }
      __builtin_amdgcn_s_setprio(0);

      // refill the just-freed set with tile k+2 ASAP (static call sites)
      if(hn2) loadA(mt + 2*MG, cur);

      if(STATS){
        #pragma unroll
        for(int nf=0; nf<2; nf++)
          #pragma unroll
          for(int mi=0; mi<2; mi++)
            #pragma unroll
            for(int r=0; r<4; r++){
              float v = acc[mi][nf][r];
              sacc[nf] += v; ssacc[nf] = fmaf(v, v, ssacc[nf]);
            }
      }

      // epilogue: two 16-row half-passes through a 4.5KB per-wave Cs slice
      unsigned short* wsc = &Cs[w][0];
      #pragma unroll
      for(int mi=0; mi<2; mi++){
        #pragma unroll
        for(int nf=0; nf<2; nf++)
          #pragma unroll
          for(int r=0; r<4; r++){
            float v = acc[mi][nf][r] + bv[nf];
            if(RELUOUT) v = fmaxf(v, 0.f);
            wsc[(q*4 + r)*36 + nf*16 + ln] = f2bf(v);
          }
        int r2 = lane >> 2, sg = lane & 3;
        uint4 u = *(const uint4*)&wsc[r2*36 + sg*8];
        *(uint4*)&C[(size_t)(m0 + mi*16 + r2)*HD + nbase + sg*8] = u;
      }
    }

    // write tile k+1 (in nxt) into the other LDS buffer
    if(hn){
      storeA(buf ^ 1, nxt);
      WAITLGKM();
    }
    BARRIER();
  };

  int k = 0;
  for(;;){
    body(k, ra, rb, 0); if(++k >= kt) break;
    body(k, rb, ra, 1); if(++k >= kt) break;
  }

  if(STATS){
    #pragma unroll
    for(int nf=0; nf<2; nf++){
      float s = sacc[nf], ss = ssacc[nf];
      s  += __shfl_xor(s, 16, 64);  s  += __shfl_xor(s, 32, 64);
      ss += __shfl_xor(ss, 16, 64); ss += __shfl_xor(ss, 32, 64);
      if(q == 0){
        int gn = nbase + nf*16 + ln;
        atomicAdd(&stats[gn], s);
        atomicAdd(&stats[HD + gn], ss);
      }
    }
  }
}

// ---------------- input projection (f32 A, K=128), B-in-registers ----------------
__global__ __launch_bounds__(256, 3) void k_gemmb_in(
    const float* __restrict__ A, const unsigned short* __restrict__ Bt,
    const float* __restrict__ bias, unsigned short* __restrict__ C)
{
  __shared__ __align__(16) unsigned short As[4096];      // 32 rows x 128 k = 8 KB
  __shared__ __align__(16) unsigned short Cs[4][1152];
  const int t = threadIdx.x;
  const int lane = t & 63, w = t >> 6;
  const int q = lane >> 4, ln = lane & 15;
  const int nh = blockIdx.x & 1;
  const int mg = blockIdx.x >> 1;
  const int nbase = nh*128 + w*32;

  bf8 bb[2][4];
  #pragma unroll
  for(int nf=0; nf<2; nf++)
    #pragma unroll
    for(int s=0; s<4; s++)
      bb[nf][s] = *(const bf8*)(Bt + (size_t)(nbase + nf*16 + ln)*FINDIM + s*32 + q*8);

  float bv[2];
  #pragma unroll
  for(int nf=0; nf<2; nf++) bv[nf] = bias[nbase + nf*16 + ln];

  for(int mt = mg; mt < NT; mt += MG){
    const int m0 = mt*32;
    const bool padt = (m0 >= NN);
    __syncthreads();
    #pragma unroll
    for(int j=0; j<2; j++){
      int slot = j*256 + t;
      int row = slot >> 4, p = slot & 15;
      int c = p ^ (row & 7);
      int gm = m0 + row;
      f4 v0 = (f4){0.f,0.f,0.f,0.f}, v1 = (f4){0.f,0.f,0.f,0.f};
      if(gm < NN){
        v0 = *(const f4*)&A[(size_t)gm*FINDIM + c*8];
        v1 = *(const f4*)&A[(size_t)gm*FINDIM + c*8 + 4];
      }
      ushort4 a0, a1;
      a0.x = f2bf(v0.x); a0.y = f2bf(v0.y); a0.z = f2bf(v0.z); a0.w = f2bf(v0.w);
      a1.x = f2bf(v1.x); a1.y = f2bf(v1.y); a1.z = f2bf(v1.z); a1.w = f2bf(v1.w);
      *(ushort4*)&As[row*128 + p*8]     = a0;
      *(ushort4*)&As[row*128 + p*8 + 4] = a1;
    }
    __syncthreads();

    f4 acc[2][2];
    #pragma unroll
    for(int i=0;i<2;i++)
      #pragma unroll
      for(int j=0;j<2;j++) acc[i][j] = (f4){0.f,0.f,0.f,0.f};

    #pragma unroll
    for(int s=0; s<4; s++){
      bf8 af[2];
      #pragma unroll
      for(int mi=0; mi<2; mi++){
        int row = mi*16 + ln;
        int p = (s*4 + q) ^ (row & 7);
        af[mi] = *(const bf8*)&As[row*128 + p*8];
      }
      #pragma unroll
      for(int mi=0; mi<2; mi++)
        #pragma unroll
        for(int nf=0; nf<2; nf++)
          acc[mi][nf] = __builtin_amdgcn_mfma_f32_16x16x32_bf16(af[mi], bb[nf][s], acc[mi][nf], 0, 0, 0);
    }

    unsigned short* wsc = &Cs[w][0];
    #pragma unroll
    for(int mi=0; mi<2; mi++)
      #pragma unroll
      for(int nf=0; nf<2; nf++)
        #pragma unroll
        for(int r=0; r<4; r++){
          float v = fmaxf(acc[mi][nf][r] + bv[nf], 0.f);
          if(padt) v = 0.f;
          wsc[(mi*16 + q*4 + r)*36 + nf*16 + ln] = f2bf(v);
        }
    int r2 = lane >> 1, ch = lane & 1;
    size_t cb = (size_t)(m0 + r2)*HD + nh*128 + w*32;
    uint4 u0 = *(const uint4*)&wsc[r2*36 + ch*8];
    uint4 u1 = *(const uint4*)&wsc[r2*36 + (ch+2)*8];
    *(uint4*)&C[cb + ch*8]     = u0;
    *(uint4*)&C[cb + (ch+2)*8] = u1;
  }
}

// ---------------- BN finalize (bias folded: stats are bias-free raw sums) ----------------
__global__ void k_bnfin(const float* __restrict__ cs, const float* __restrict__ bias,
                        const float* __restrict__ g, const float* __restrict__ be,
                        float* __restrict__ sc, float* __restrict__ sh){
  int c = threadIdx.x;
  float m0 = cs[c] * (1.0f/NN);
  float mean = m0 + bias[c];
  float var  = cs[HD + c] * (1.0f/NN) - m0*m0;
  float s = g[c] * rsqrtf(var + 1e-5f);
  sc[c] = s;
  sh[c] = be[c] - mean*s;
}

// ---------------- aggregation: half-wave split, 16B lanes, packed-f32 math ----------------
__device__ __forceinline__ void acc8p(f2 (&ac)[4], uint4 u, f2 wt,
                                      const f2 (&s)[4], const f2 (&sh)[4], int ident){
  const unsigned* ws = (const unsigned*)&u;
  #pragma unroll
  for(int i=0;i<4;i++){
    f2 v = up2(ws[i]);
    if(!ident){
      v = pk_fma(s[i], v, sh[i]);          // BN scale/shift (2 ch/op)
      v.x = fmaxf(v.x, 0.f);               // ReLU (no packed f32 max on gfx9)
      v.y = fmaxf(v.y, 0.f);
    }
    ac[i] = pk_fma(wt, v, ac[i]);          // weighted accumulate (2 ch/op)
  }
}

__global__ __launch_bounds__(256) void k_agg(const unsigned short* __restrict__ src,
    unsigned short* __restrict__ dst,
    const int* __restrict__ offs, const int* __restrict__ eidx,
    const float* __restrict__ eps, int l,
    const float* __restrict__ sc, const float* __restrict__ sh, int ident)
{
  int wv = threadIdx.x >> 6;
  int n = blockIdx.x*4 + wv;
  if(n >= NN) return;
  int lane = threadIdx.x & 63;
  int h = lane >> 5, l5 = lane & 31;
  int c = l5 * 8;

  f2 s[4] = {(f2){0.f,0.f},(f2){0.f,0.f},(f2){0.f,0.f},(f2){0.f,0.f}};
  f2 sf[4] = {(f2){0.f,0.f},(f2){0.f,0.f},(f2){0.f,0.f},(f2){0.f,0.f}};
  if(!ident){
    #pragma unroll
    for(int i=0;i<4;i++){
      s[i]  = *(const f2*)(sc + c + 2*i);
      sf[i] = *(const f2*)(sh + c + 2*i);
    }
  }
  float ep = 1.f + eps[l];
  f2 epw = (f2){ep, ep};
  f2 one = (f2){1.f, 1.f};

  f2 ac[4] = {(f2){0.f,0.f},(f2){0.f,0.f},(f2){0.f,0.f},(f2){0.f,0.f}};
  int lo = offs[n], hi = offs[n+1];

  bool first = true;
  for(int base = lo; first || base < hi; base += 64){
    int cnt = hi - base; if(cnt > 64) cnt = 64; if(cnt < 0) cnt = 0;
    int R = cnt + (first ? 1 : 0);          // virtual rows (self included once)
    int idx = (base + lane < hi) ? eidx[base + lane] : 0;
    for(int r0 = 0; r0 < R; r0 += 4){
      int my0 = r0 + h, my1 = r0 + 2 + h;
      bool v0 = my0 < R, v1 = my1 < R;
      bool self0 = first && (my0 == 0);
      int j0 = (first ? my0 - 1 : my0) & 63;
      int j1 = (first ? my1 - 1 : my1) & 63;
      int sr0 = __shfl(idx, j0, 64);
      int sr1 = __shfl(idx, j1, 64);
      int row0 = self0 ? n : sr0;
      f2 w0 = self0 ? epw : one;
      uint4 u0, u1;
      if(v0) u0 = *(const uint4*)(src + (size_t)row0*HD + c);
      if(v1) u1 = *(const uint4*)(src + (size_t)sr1*HD + c);
      if(v0) acc8p(ac, u0, w0, s, sf, ident);
      if(v1) acc8p(ac, u1, one, s, sf, ident);
    }
    first = false;
  }

  // merge the two halves (lane l and l^32 hold the same channel set)
  #pragma unroll
  for(int i=0;i<4;i++){
    ac[i].x += __shfl_xor(ac[i].x, 32, 64);
    ac[i].y += __shfl_xor(ac[i].y, 32, 64);
  }
  if(h == 0){
    unsigned short o[8];
    #pragma unroll
    for(int i=0;i<4;i++){ o[2*i] = f2bf(ac[i].x); o[2*i+1] = f2bf(ac[i].y); }
    *(uint4*)(dst + (size_t)n*HD + c) = *(const uint4*)o;
  }
}

// ---------------- pooling ----------------
__device__ __forceinline__ int lowb(const int* __restrict__ arr, int n, int key){
  int lo = 0, hi = n;
  while(lo < hi){ int mid = (lo + hi) >> 1; if(arr[mid] < key) lo = mid + 1; else hi = mid; }
  return lo;
}

__global__ __launch_bounds__(256) void k_pool(const unsigned short* __restrict__ src,
    const int* __restrict__ batch,
    const float* __restrict__ sc, const float* __restrict__ sh, float* __restrict__ pooled)
{
  int wv = threadIdx.x >> 6;
  int g = blockIdx.x*4 + wv;
  if(g >= NG) return;
  int lane = threadIdx.x & 63;
  int c = lane << 2;
  int lo = lowb(batch, NN, g);
  int hi = lowb(batch, NN, g+1);
  f4 s4 = *(const f4*)(sc + c);
  f4 t4 = *(const f4*)(sh + c);
  f4 acc = (f4){0.f,0.f,0.f,0.f};
  for(int n=lo; n<hi; n++){
    ushort4 uv = *(const ushort4*)(src + (size_t)n*HD + c);
    acc.x += fmaxf(fmaf(s4.x, bf2f(uv.x), t4.x), 0.f);
    acc.y += fmaxf(fmaf(s4.y, bf2f(uv.y), t4.y), 0.f);
    acc.z += fmaxf(fmaf(s4.z, bf2f(uv.z), t4.z), 0.f);
    acc.w += fmaxf(fmaf(s4.w, bf2f(uv.w), t4.w), 0.f);
  }
  float inv = 1.0f / fmaxf((float)(hi - lo), 1.0f);
  acc.x *= inv; acc.y *= inv; acc.z *= inv; acc.w *= inv;
  *(f4*)(pooled + (size_t)g*HD + c) = acc;
}

// ---------------- head ----------------
__global__ __launch_bounds__(128) void k_head(const float* __restrict__ pooled,
    const float* __restrict__ W1, const float* __restrict__ b1,
    const float* __restrict__ W2, const float* __restrict__ b2, float* __restrict__ out)
{
  __shared__ float p[HD];
  __shared__ float red[2];
  int g = blockIdx.x, t = threadIdx.x;
  if(t < 64) *(f4*)&p[t*4] = *(const f4*)(pooled + (size_t)g*HD + t*4);
  __syncthreads();
  float s = b1[t];
  for(int k=0;k<HD;k++) s = fmaf(p[k], W1[k*128 + t], s);
  float o = fmaxf(s, 0.f) * W2[t];
  #pragma unroll
  for(int d=1; d<64; d<<=1) o += __shfl_xor(o, d, 64);
  if((t & 63) == 0) red[t>>6] = o;
  __syncthreads();
  if(t == 0) out[g] = red[0] + red[1] + b2[0];
}

// ---------------- launch ----------------
extern "C" void kernel_launch(void* const* d_in, const int* in_sizes, int n_in,
                              void* d_out, int out_size, void* d_ws, size_t ws_size,
                              hipStream_t stream) {
  const float* x    = (const float*)d_in[0];
  const int*   ei   = (const int*)  d_in[1];
  const int*   bat  = (const int*)  d_in[2];
  const float* inW  = (const float*)d_in[3];
  const float* inb  = (const float*)d_in[4];
  const float* W1   = (const float*)d_in[5];
  const float* b1   = (const float*)d_in[6];
  const float* g1   = (const float*)d_in[7];
  const float* be1  = (const float*)d_in[8];
  const float* W2   = (const float*)d_in[9];
  const float* b2   = (const float*)d_in[10];
  const float* g2   = (const float*)d_in[11];
  const float* be2  = (const float*)d_in[12];
  const float* eps  = (const float*)d_in[13];
  const float* hW1  = (const float*)d_in[14];
  const float* hb1  = (const float*)d_in[15];
  const float* hW2  = (const float*)d_in[16];
  const float* hb2  = (const float*)d_in[17];
  float* out = (float*)d_out;

  char* p = (char*)d_ws;
  auto alloc = [&](size_t bytes)->char*{
    char* r = p; p += (bytes + 255) & ~(size_t)255; return r;
  };
  unsigned short* B0 = (unsigned short*)alloc((size_t)MPAD*HD*2);
  unsigned short* B1 = (unsigned short*)alloc((size_t)MPAD*HD*2);
  unsigned short* Wtin = (unsigned short*)alloc((size_t)FINDIM*HD*2);
  unsigned short* Wt1  = (unsigned short*)alloc((size_t)NLAYER*HD*HD*2);
  unsigned short* Wt2  = (unsigned short*)alloc((size_t)NLAYER*HD*HD*2);
  int* counts  = (int*)alloc((size_t)NN*4);
  int* offsets = (int*)alloc((size_t)(NN+1)*4);
  int* cursor  = (int*)alloc((size_t)NN*4);
  int* eidx    = (int*)alloc((size_t)NE*4);
  int* partials= (int*)alloc(128*4);
  float* cs    = (float*)alloc(4*HD*4);
  float* bnp   = (float*)alloc(4*HD*4);
  float* pooled= (float*)alloc((size_t)NG*HD*4);

  // CSR build
  k_zero<<<(NN+255)/256, 256, 0, stream>>>(counts, NN);
  k_count<<<(NE+255)/256, 256, 0, stream>>>(ei, counts);
  int nb = (NN + 1023)/1024;
  k_scan_partial<<<nb, 256, 0, stream>>>(counts, partials);
  k_scan_tot<<<1, 128, 0, stream>>>(partials, offsets, nb);
  k_scan_final<<<nb, 256, 0, stream>>>(counts, partials, offsets, cursor);
  k_fill<<<(NE+255)/256, 256, 0, stream>>>(ei, cursor, eidx);

  // weights -> bf16 [n][k]
  k_wt<<<dim3((FINDIM*HD+255)/256, 1), 256, 0, stream>>>(inW, Wtin, FINDIM, HD);
  k_wt<<<dim3((HD*HD+255)/256, NLAYER), 256, 0, stream>>>(W1, Wt1, HD, HD);
  k_wt<<<dim3((HD*HD+255)/256, NLAYER), 256, 0, stream>>>(W2, Wt2, HD, HD);

  // zero pad rows of B1 once (B0's pad established by gemm_in epilogue)
  {
    int padInts = (MPAD - NN) * HD / 2;
    k_zero<<<(padInts+255)/256, 256, 0, stream>>>((int*)(B1 + (size_t)NN*HD), padInts);
  }

  k_gemmb_in<<<2*MG, 256, 0, stream>>>(x, Wtin, inb, B0);

  float* sc1 = bnp, *sh1 = bnp + HD, *sc2 = bnp + 2*HD, *sh2 = bnp + 3*HD;
  unsigned short* hbuf = B0;
  unsigned short* tbuf = B1;
  for(int l=0; l<NLAYER; l++){
    k_zero<<<4, 256, 0, stream>>>((int*)cs, 4*HD);
    k_agg<<<(NN+3)/4, 256, 0, stream>>>(hbuf, tbuf, offsets, eidx, eps, l, sc2, sh2, l==0 ? 1 : 0);
    k_gemmb<0, false, true><<<2*MG, 256, 0, stream>>>(tbuf, Wt1 + (size_t)l*HD*HD, b1 + l*HD,
                                                      nullptr, nullptr, hbuf, cs);
    k_bnfin<<<1, HD, 0, stream>>>(cs, b1 + l*HD, g1 + l*HD, be1 + l*HD, sc1, sh1);
    k_gemmb<1, false, true><<<2*MG, 256, 0, stream>>>(hbuf, Wt2 + (size_t)l*HD*HD, b2 + l*HD,
                                                      sc1, sh1, tbuf, cs + 2*HD);
    k_bnfin<<<1, HD, 0, stream>>>(cs + 2*HD, b2 + l*HD, g2 + l*HD, be2 + l*HD, sc2, sh2);
    unsigned short* tmp = hbuf; hbuf = tbuf; tbuf = tmp;
  }

  k_pool<<<(NG+3)/4, 256, 0, stream>>>(hbuf, bat, sc2, sh2, pooled);
  k_head<<<NG, 128, 0, stream>>>(pooled, hW1, hb1, hW2, hb2, out);
}